// Round 19
// baseline (44.204 us; speedup 1.0000x reference)
//
#include <hip/hip_runtime.h>
#include <hip/hip_bf16.h>
#include <math.h>

#define C2 2.8853900817779268f   // 2*log2(e)

__device__ __forceinline__ unsigned int pack_bf16(float a, float b) {
    __hip_bfloat162 h = __float22bfloat162_rn(float2{a, b});   // v_cvt_pk_bf16_f32 (RNE)
    return *reinterpret_cast<unsigned int*>(&h);
}

// 512 blocks x 256 thr (4 waves x 4 q rows = 16 rows/block), 80 KB LDS ->
// TWO desynchronized blocks per CU. Ek stored bf16-packed (RNE) in kbuf.
// One barrier per block; strips wave-private; softmax/PV barrier-free.
__global__ __launch_bounds__(256, 2) void addattn_kernel(
    const float* __restrict__ q_g, const float* __restrict__ k_g,
    const float* __restrict__ v_g, const float* __restrict__ w_g,
    float* __restrict__ out)
{
    __shared__ unsigned int kbuf[16384];  // 64 KB: Ek bf16 pairs [t4][g32][rot64][2]
    __shared__ float sB[4096];            // 16 KB: 4 waves x 1024f strip (Eq[4][128]|w -> attn[4][256])

    const int tid  = threadIdx.x;        // 0..255
    const int lane = tid & 63;
    const int wv   = __builtin_amdgcn_readfirstlane(tid >> 6);  // 0..3 uniform

    // XCD-grouped remap: XCD x serves batches 4x..4x+3 (K/V/Q L2-resident)
    const int o   = ((blockIdx.x & 7) << 6) + (blockIdx.x >> 3);  // 0..511
    const int b   = o >> 4;
    const int qr0 = ((o & 15) << 4) + (wv << 2);   // wave's 4 q rows

    float* strip = sB + (wv << 10);   // 1024 floats, wave-private

    // ---- strip: w copy at [512..640), Eq[4][128] at [0..512) ----
    if (lane < 32) *(float4*)&strip[512 + (lane << 2)] = ((const float4*)w_g)[lane];
    {
        const float* qb = q_g + (size_t)(b * 256 + qr0) * 128;
        #pragma unroll
        for (int j = 0; j < 2; ++j) {
            int f = lane + (j << 6);
            int r = f >> 5, c = f & 31;
            float4 qv = *(const float4*)(qb + (r << 7) + (c << 2));
            float4 E;
            E.x = __builtin_amdgcn_exp2f(C2 * qv.x);
            E.y = __builtin_amdgcn_exp2f(C2 * qv.y);
            E.z = __builtin_amdgcn_exp2f(C2 * qv.z);
            E.w = __builtin_amdgcn_exp2f(C2 * qv.w);
            *(float4*)&strip[(r << 7) + (c << 2)] = E;
        }
    }

    // ---- stage K[b]: load -> exp2 -> RNE bf16 pack -> rotation-swizzled kbuf ----
    {
        const float4* kg4 = (const float4*)(k_g + (size_t)b * 32768);
        #pragma unroll 8
        for (int j = 0; j < 32; ++j) {
            int f = tid + (j << 8);            // 0..8191 float4s
            float4 kv = kg4[f];
            int k = f >> 5, g = f & 31;
            float e0 = __builtin_amdgcn_exp2f(C2 * kv.x);
            float e1 = __builtin_amdgcn_exp2f(C2 * kv.y);
            float e2 = __builtin_amdgcn_exp2f(C2 * kv.z);
            float e3 = __builtin_amdgcn_exp2f(C2 * kv.w);
            uint2 p;
            p.x = pack_bf16(e0, e1);
            p.y = pack_bf16(e2, e3);
            int rot = ((k & 63) + g) & 63;
            int pair = ((((k >> 6) << 5) | g) << 6) + rot;   // [t][g][rot]
            *(uint2*)&kbuf[pair << 1] = p;
        }
    }
    __syncthreads();    // the only barrier (per block; blocks on a CU desync)

    // ---- score: g outer, t inner; 16 accumulators [t][r]; bf16 unpack ----
    float s[4][4];
    #pragma unroll
    for (int t = 0; t < 4; ++t)
        #pragma unroll
        for (int r = 0; r < 4; ++r) s[t][r] = 0.f;

    #pragma unroll 4
    for (int g = 0; g < 32; ++g) {
        float4 w4 = *(const float4*)&strip[512 + (g << 2)];   // bcast
        float4 e0 = *(const float4*)&strip[g << 2];
        float4 e1 = *(const float4*)&strip[128 + (g << 2)];
        float4 e2 = *(const float4*)&strip[256 + (g << 2)];
        float4 e3 = *(const float4*)&strip[384 + (g << 2)];
        const int rot = (lane + g) & 63;
        #pragma unroll
        for (int t = 0; t < 4; ++t) {
            uint2 kp = *(const uint2*)&kbuf[(((((t << 5) | g) << 6) + rot) << 1)];
            float k0 = __uint_as_float(kp.x << 16);
            float k1 = __uint_as_float(kp.x & 0xFFFF0000u);
            float k2 = __uint_as_float(kp.y << 16);
            float k3 = __uint_as_float(kp.y & 0xFFFF0000u);
            #define RB(E, S)                                                   \
            {                                                                  \
                float d0 = fmaf(E.x, k0, 1.f), d1 = fmaf(E.y, k1, 1.f);        \
                float d2 = fmaf(E.z, k2, 1.f), d3 = fmaf(E.w, k3, 1.f);        \
                float P01 = d0 * d1, P23 = d2 * d3;                            \
                float N01 = fmaf(w4.x, d1, w4.y * d0);                         \
                float N23 = fmaf(w4.z, d3, w4.w * d2);                         \
                float num = fmaf(N01, P23, N23 * P01);                         \
                S = fmaf(num, __builtin_amdgcn_rcpf(P01 * P23), S);            \
            }
            RB(e0, s[t][0])
            RB(e1, s[t][1])
            RB(e2, s[t][2])
            RB(e3, s[t][3])
            #undef RB
        }
    }

    // ---- softmax per row (lane holds k = 64t+lane); attn overlays strip ----
    #pragma unroll
    for (int r = 0; r < 4; ++r) {
        float x0 = -C2 * s[0][r], x1 = -C2 * s[1][r];
        float x2 = -C2 * s[2][r], x3 = -C2 * s[3][r];
        float m = fmaxf(fmaxf(x0, x1), fmaxf(x2, x3));
        #pragma unroll
        for (int off = 32; off; off >>= 1) m = fmaxf(m, __shfl_xor(m, off));
        float e0 = __builtin_amdgcn_exp2f(x0 - m);
        float e1 = __builtin_amdgcn_exp2f(x1 - m);
        float e2 = __builtin_amdgcn_exp2f(x2 - m);
        float e3 = __builtin_amdgcn_exp2f(x3 - m);
        float sum = (e0 + e1) + (e2 + e3);
        #pragma unroll
        for (int off = 32; off; off >>= 1) sum += __shfl_xor(sum, off);
        float inv = __builtin_amdgcn_rcpf(sum);
        strip[(r << 8) + lane]       = e0 * inv;   // own-wave ds ordering
        strip[(r << 8) + 64 + lane]  = e1 * inv;
        strip[(r << 8) + 128 + lane] = e2 * inv;
        strip[(r << 8) + 192 + lane] = e3 * inv;
    }

    // ---- PV: lane = h-pair (h = 2*lane, 2*lane+1); V f32 global (L1/L2-hot) ----
    float2 o0, o1, o2, o3;
    o0.x = o0.y = o1.x = o1.y = 0.f;
    o2.x = o2.y = o3.x = o3.y = 0.f;
    const float2* vp = (const float2*)(v_g + (size_t)b * 32768) + lane;
    #pragma unroll 4
    for (int j4 = 0; j4 < 64; ++j4) {
        float4 a0 = *(const float4*)(strip + (j4 << 2));          // row bcasts
        float4 a1 = *(const float4*)(strip + 256 + (j4 << 2));
        float4 a2 = *(const float4*)(strip + 512 + (j4 << 2));
        float4 a3 = *(const float4*)(strip + 768 + (j4 << 2));
        #pragma unroll
        for (int i = 0; i < 4; ++i) {
            float2 v2 = vp[((j4 << 2) + i) << 6];                 // 512B coalesced
            float c0 = (&a0.x)[i], c1 = (&a1.x)[i], c2 = (&a2.x)[i], c3 = (&a3.x)[i];
            o0.x = fmaf(c0, v2.x, o0.x); o0.y = fmaf(c0, v2.y, o0.y);
            o1.x = fmaf(c1, v2.x, o1.x); o1.y = fmaf(c1, v2.y, o1.y);
            o2.x = fmaf(c2, v2.x, o2.x); o2.y = fmaf(c2, v2.y, o2.y);
            o3.x = fmaf(c3, v2.x, o3.x); o3.y = fmaf(c3, v2.y, o3.y);
        }
    }

    float* ob = out + (size_t)(b * 256 + qr0) * 128 + (lane << 1);
    *(float2*)(ob)       = o0;
    *(float2*)(ob + 128) = o1;
    *(float2*)(ob + 256) = o2;
    *(float2*)(ob + 384) = o3;
}

extern "C" void kernel_launch(void* const* d_in, const int* in_sizes, int n_in,
                              void* d_out, int out_size, void* d_ws, size_t ws_size,
                              hipStream_t stream) {
    const float* q = (const float*)d_in[0];
    const float* k = (const float*)d_in[1];
    const float* v = (const float*)d_in[2];
    const float* w = (const float*)d_in[3];
    float* out = (float*)d_out;
    addattn_kernel<<<512, 256, 0, stream>>>(q, k, v, w, out);
}

// Round 20
// 44.159 us; speedup vs baseline: 1.0010x; 1.0010x over previous
//
#include <hip/hip_runtime.h>
#include <math.h>

#define C2 2.8853900817779268f   // 2*log2(e)

// 256 blocks x 512 thr (8 waves x 4 q rows), 1 block/CU, 160 KB LDS.
// Phase 1: stage K[b] -> exp2 -> rotation-swizzled kbuf; prefetch ALL of V[b]
//          into 64 VGPRs (T14: latency hides under score).
// Phase 2: score (g-outer/t-inner, all-K-resident), softmax (wave-private).
// Phase 3: V regs -> kbuf (Ek dead), PV entirely from LDS (b64 reads).
__global__ __launch_bounds__(512) void addattn_kernel(
    const float* __restrict__ q_g, const float* __restrict__ k_g,
    const float* __restrict__ v_g, const float* __restrict__ w_g,
    float* __restrict__ out)
{
    __shared__ float kbuf[32768];   // 128 KB: Ek[t4][g32][rot64][hi4] -> V[256][128]
    __shared__ float sB[8192];      //  32 KB: 8 waves x 1024f strip (Eq|w -> attn[4][256])

    const int tid  = threadIdx.x;
    const int lane = tid & 63;
    const int wv   = __builtin_amdgcn_readfirstlane(tid >> 6);  // 0..7 uniform

    // XCD-grouped remap: XCD x serves batches 4x..4x+3 (K/V/Q L2-resident)
    const int xcd = blockIdx.x & 7;
    const int sub = blockIdx.x >> 3;          // 0..31
    const int b   = (xcd << 2) + (sub >> 3);
    const int qr0 = ((sub & 7) << 5) + (wv << 2);   // wave's 4 q rows

    float* strip = sB + (wv << 10);   // 1024 floats, wave-private

    // ---- strip: w copy at [512..640), Eq[4][128] at [0..512) ----
    if (lane < 32) *(float4*)&strip[512 + (lane << 2)] = ((const float4*)w_g)[lane];
    {
        const float* qb = q_g + (size_t)(b * 256 + qr0) * 128;
        #pragma unroll
        for (int j = 0; j < 2; ++j) {
            int f = lane + (j << 6);
            int r = f >> 5, c = f & 31;
            float4 qv = *(const float4*)(qb + (r << 7) + (c << 2));
            float4 E;
            E.x = __builtin_amdgcn_exp2f(C2 * qv.x);
            E.y = __builtin_amdgcn_exp2f(C2 * qv.y);
            E.z = __builtin_amdgcn_exp2f(C2 * qv.z);
            E.w = __builtin_amdgcn_exp2f(C2 * qv.w);
            *(float4*)&strip[(r << 7) + (c << 2)] = E;
        }
    }

    // ---- stage K[b]: load -> exp2 -> rotation-swizzled kbuf (conflict-free) ----
    {
        const float4* kg4 = (const float4*)(k_g + (size_t)b * 32768);
        #pragma unroll
        for (int j = 0; j < 16; ++j) {
            int f = tid + (j << 9);            // 0..8191 float4s
            float4 kv = kg4[f];
            int k = f >> 5, g = f & 31;
            float4 E;
            E.x = __builtin_amdgcn_exp2f(C2 * kv.x);
            E.y = __builtin_amdgcn_exp2f(C2 * kv.y);
            E.z = __builtin_amdgcn_exp2f(C2 * kv.z);
            E.w = __builtin_amdgcn_exp2f(C2 * kv.w);
            int rot = ((k & 63) + g) & 63;
            *(float4*)&kbuf[((k >> 6) << 13) + (g << 8) + (rot << 2)] = E;
        }
    }

    // ---- T14: prefetch ALL of V[b] into registers (latency hides under score) ----
    const float4* vg4 = (const float4*)(v_g + (size_t)b * 32768);
    float4 pv0  = vg4[tid];
    float4 pv1  = vg4[tid + 512];
    float4 pv2  = vg4[tid + 1024];
    float4 pv3  = vg4[tid + 1536];
    float4 pv4  = vg4[tid + 2048];
    float4 pv5  = vg4[tid + 2560];
    float4 pv6  = vg4[tid + 3072];
    float4 pv7  = vg4[tid + 3584];
    float4 pv8  = vg4[tid + 4096];
    float4 pv9  = vg4[tid + 4608];
    float4 pv10 = vg4[tid + 5120];
    float4 pv11 = vg4[tid + 5632];
    float4 pv12 = vg4[tid + 6144];
    float4 pv13 = vg4[tid + 6656];
    float4 pv14 = vg4[tid + 7168];
    float4 pv15 = vg4[tid + 7680];

    __syncthreads();    // barrier 1: kbuf Ek visible

    // ---- score: g outer, t inner; 16 accumulators [t][r] ----
    float s[4][4];
    #pragma unroll
    for (int t = 0; t < 4; ++t)
        #pragma unroll
        for (int r = 0; r < 4; ++r) s[t][r] = 0.f;

    #pragma unroll 4
    for (int g = 0; g < 32; ++g) {
        float4 w4 = *(const float4*)&strip[512 + (g << 2)];   // bcast
        float4 e0 = *(const float4*)&strip[g << 2];
        float4 e1 = *(const float4*)&strip[128 + (g << 2)];
        float4 e2 = *(const float4*)&strip[256 + (g << 2)];
        float4 e3 = *(const float4*)&strip[384 + (g << 2)];
        const int rot = (((lane + g) & 63) << 2) + (g << 8);
        #pragma unroll
        for (int t = 0; t < 4; ++t) {
            float4 k4 = *(const float4*)&kbuf[(t << 13) + rot];
            #define RB(E, S)                                                   \
            {                                                                  \
                float d0 = fmaf(E.x, k4.x, 1.f), d1 = fmaf(E.y, k4.y, 1.f);    \
                float d2 = fmaf(E.z, k4.z, 1.f), d3 = fmaf(E.w, k4.w, 1.f);    \
                float P01 = d0 * d1, P23 = d2 * d3;                            \
                float N01 = fmaf(w4.x, d1, w4.y * d0);                         \
                float N23 = fmaf(w4.z, d3, w4.w * d2);                         \
                float num = fmaf(N01, P23, N23 * P01);                         \
                S = fmaf(num, __builtin_amdgcn_rcpf(P01 * P23), S);            \
            }
            RB(e0, s[t][0])
            RB(e1, s[t][1])
            RB(e2, s[t][2])
            RB(e3, s[t][3])
            #undef RB
        }
    }

    // ---- softmax per row (lane holds k = 64t+lane); attn overlays strip ----
    #pragma unroll
    for (int r = 0; r < 4; ++r) {
        float x0 = -C2 * s[0][r], x1 = -C2 * s[1][r];
        float x2 = -C2 * s[2][r], x3 = -C2 * s[3][r];
        float m = fmaxf(fmaxf(x0, x1), fmaxf(x2, x3));
        #pragma unroll
        for (int off = 32; off; off >>= 1) m = fmaxf(m, __shfl_xor(m, off));
        float e0 = __builtin_amdgcn_exp2f(x0 - m);
        float e1 = __builtin_amdgcn_exp2f(x1 - m);
        float e2 = __builtin_amdgcn_exp2f(x2 - m);
        float e3 = __builtin_amdgcn_exp2f(x3 - m);
        float sum = (e0 + e1) + (e2 + e3);
        #pragma unroll
        for (int off = 32; off; off >>= 1) sum += __shfl_xor(sum, off);
        float inv = __builtin_amdgcn_rcpf(sum);
        strip[(r << 8) + lane]       = e0 * inv;   // own-wave ds ordering
        strip[(r << 8) + 64 + lane]  = e1 * inv;
        strip[(r << 8) + 128 + lane] = e2 * inv;
        strip[(r << 8) + 192 + lane] = e3 * inv;
    }

    __syncthreads();    // barrier 2: all kbuf Ek reads done

    // ---- V regs -> kbuf linear [256][128] (conflict-free b128 writes) ----
    ((float4*)kbuf)[tid]        = pv0;
    ((float4*)kbuf)[tid + 512]  = pv1;
    ((float4*)kbuf)[tid + 1024] = pv2;
    ((float4*)kbuf)[tid + 1536] = pv3;
    ((float4*)kbuf)[tid + 2048] = pv4;
    ((float4*)kbuf)[tid + 2560] = pv5;
    ((float4*)kbuf)[tid + 3072] = pv6;
    ((float4*)kbuf)[tid + 3584] = pv7;
    ((float4*)kbuf)[tid + 4096] = pv8;
    ((float4*)kbuf)[tid + 4608] = pv9;
    ((float4*)kbuf)[tid + 5120] = pv10;
    ((float4*)kbuf)[tid + 5632] = pv11;
    ((float4*)kbuf)[tid + 6144] = pv12;
    ((float4*)kbuf)[tid + 6656] = pv13;
    ((float4*)kbuf)[tid + 7168] = pv14;
    ((float4*)kbuf)[tid + 7680] = pv15;

    __syncthreads();    // barrier 3: V visible

    // ---- PV entirely from LDS: lane = h-pair (h = 2*lane, 2*lane+1) ----
    float2 o0, o1, o2, o3;
    o0.x = o0.y = o1.x = o1.y = 0.f;
    o2.x = o2.y = o3.x = o3.y = 0.f;
    #pragma unroll 4
    for (int j4 = 0; j4 < 64; ++j4) {
        float4 a0 = *(const float4*)(strip + (j4 << 2));          // row bcasts
        float4 a1 = *(const float4*)(strip + 256 + (j4 << 2));
        float4 a2 = *(const float4*)(strip + 512 + (j4 << 2));
        float4 a3 = *(const float4*)(strip + 768 + (j4 << 2));
        #pragma unroll
        for (int i = 0; i < 4; ++i) {
            float2 v2 = *(const float2*)&kbuf[(((j4 << 2) + i) << 7) + (lane << 1)];
            float c0 = (&a0.x)[i], c1 = (&a1.x)[i], c2 = (&a2.x)[i], c3 = (&a3.x)[i];
            o0.x = fmaf(c0, v2.x, o0.x); o0.y = fmaf(c0, v2.y, o0.y);
            o1.x = fmaf(c1, v2.x, o1.x); o1.y = fmaf(c1, v2.y, o1.y);
            o2.x = fmaf(c2, v2.x, o2.x); o2.y = fmaf(c2, v2.y, o2.y);
            o3.x = fmaf(c3, v2.x, o3.x); o3.y = fmaf(c3, v2.y, o3.y);
        }
    }

    float* ob = out + (size_t)(b * 256 + qr0) * 128 + (lane << 1);
    *(float2*)(ob)       = o0;
    *(float2*)(ob + 128) = o1;
    *(float2*)(ob + 256) = o2;
    *(float2*)(ob + 384) = o3;
}

extern "C" void kernel_launch(void* const* d_in, const int* in_sizes, int n_in,
                              void* d_out, int out_size, void* d_ws, size_t ws_size,
                              hipStream_t stream) {
    const float* q = (const float*)d_in[0];
    const float* k = (const float*)d_in[1];
    const float* v = (const float*)d_in[2];
    const float* w = (const float*)d_in[3];
    float* out = (float*)d_out;
    addattn_kernel<<<256, 512, 0, stream>>>(q, k, v, w, out);
}

// Round 21
// 42.201 us; speedup vs baseline: 1.0475x; 1.0464x over previous
//
#include <hip/hip_runtime.h>
#include <math.h>

#define C2 2.8853900817779268f   // 2*log2(e)

typedef float f32x2 __attribute__((ext_vector_type(2)));

// 256 blocks x 512 thr (8 waves x 4 q rows), 1 block/CU, 160 KB LDS.
// r18 structure + packed-fp32 score: rows (0,1) and (2,3) computed as f32x2
// lanes of v_pk_fma_f32/v_pk_mul_f32 (ffp-contract=fast). Eq stored
// interleaved [h][4 rows] so row-pairs are natural b64 LDS broadcasts.
__global__ __launch_bounds__(512) void addattn_kernel(
    const float* __restrict__ q_g, const float* __restrict__ k_g,
    const float* __restrict__ v_g, const float* __restrict__ w_g,
    float* __restrict__ out)
{
    __shared__ float kbuf[32768];   // 128 KB: Ek[t4][g32][rot64][hi4]
    __shared__ float sB[8192];      //  32 KB: 8 waves x 1024f strip:
                                    //  Eq[h128][r4] at [0..512) | w[128] at [512..640) -> attn[4][256]

    const int tid  = threadIdx.x;
    const int lane = tid & 63;
    const int wv   = __builtin_amdgcn_readfirstlane(tid >> 6);  // 0..7 uniform

    // XCD-grouped remap: XCD x serves batches 4x..4x+3 (K/V/Q L2-resident)
    const int xcd = blockIdx.x & 7;
    const int sub = blockIdx.x >> 3;          // 0..31
    const int b   = (xcd << 2) + (sub >> 3);
    const int qr0 = ((sub & 7) << 5) + (wv << 2);   // wave's 4 q rows

    float* strip = sB + (wv << 10);   // 1024 floats, wave-private

    // ---- strip: w at [512..640); Eq interleaved [h][r] at [0..512) ----
    if (lane < 32) *(float4*)&strip[512 + (lane << 2)] = ((const float4*)w_g)[lane];
    {
        const float* qb = q_g + (size_t)(b * 256 + qr0) * 128;
        #pragma unroll
        for (int j = 0; j < 2; ++j) {
            int f = lane + (j << 6);
            int r = f >> 5, c = f & 31;          // row r, h-quad c
            float4 qv = *(const float4*)(qb + (r << 7) + (c << 2));
            strip[(c << 4) + 0  + r] = __builtin_amdgcn_exp2f(C2 * qv.x);
            strip[(c << 4) + 4  + r] = __builtin_amdgcn_exp2f(C2 * qv.y);
            strip[(c << 4) + 8  + r] = __builtin_amdgcn_exp2f(C2 * qv.z);
            strip[(c << 4) + 12 + r] = __builtin_amdgcn_exp2f(C2 * qv.w);
        }
    }

    // ---- stage K[b]: load -> exp2 -> rotation-swizzled kbuf (conflict-free) ----
    {
        const float4* kg4 = (const float4*)(k_g + (size_t)b * 32768);
        #pragma unroll
        for (int j = 0; j < 16; ++j) {
            int f = tid + (j << 9);            // 0..8191 float4s
            float4 kv = kg4[f];
            int k = f >> 5, g = f & 31;
            float4 E;
            E.x = __builtin_amdgcn_exp2f(C2 * kv.x);
            E.y = __builtin_amdgcn_exp2f(C2 * kv.y);
            E.z = __builtin_amdgcn_exp2f(C2 * kv.z);
            E.w = __builtin_amdgcn_exp2f(C2 * kv.w);
            int rot = ((k & 63) + g) & 63;
            *(float4*)&kbuf[((k >> 6) << 13) + (g << 8) + (rot << 2)] = E;
        }
    }
    __syncthreads();    // barrier 1 (only barrier)

    // ---- score: g outer, t inner; packed row-pairs sA (rows 0,1) / sB23 (rows 2,3) ----
    const f32x2 one = {1.0f, 1.0f};
    f32x2 accA[4], accB[4];
    #pragma unroll
    for (int t = 0; t < 4; ++t) { accA[t] = (f32x2){0.f, 0.f}; accB[t] = (f32x2){0.f, 0.f}; }

    #pragma unroll 4
    for (int g = 0; g < 32; ++g) {
        float4 w4 = *(const float4*)&strip[512 + (g << 2)];      // bcast b128
        f32x2 w0s = {w4.x, w4.x}, w1s = {w4.y, w4.y};
        f32x2 w2s = {w4.z, w4.z}, w3s = {w4.w, w4.w};
        const int eb = g << 4;                                   // Eq base: [h=4g..][r]
        f32x2 eA0 = *(const f32x2*)&strip[eb + 0],  eB0 = *(const f32x2*)&strip[eb + 2];
        f32x2 eA1 = *(const f32x2*)&strip[eb + 4],  eB1 = *(const f32x2*)&strip[eb + 6];
        f32x2 eA2 = *(const f32x2*)&strip[eb + 8],  eB2 = *(const f32x2*)&strip[eb + 10];
        f32x2 eA3 = *(const f32x2*)&strip[eb + 12], eB3 = *(const f32x2*)&strip[eb + 14];
        const int rot = (((lane + g) & 63) << 2) + (g << 8);
        #pragma unroll
        for (int t = 0; t < 4; ++t) {
            float4 k4 = *(const float4*)&kbuf[(t << 13) + rot];
            f32x2 k0s = {k4.x, k4.x}, k1s = {k4.y, k4.y};
            f32x2 k2s = {k4.z, k4.z}, k3s = {k4.w, k4.w};
            #define RBPK(E0, E1, E2, E3, S)                                    \
            {                                                                  \
                f32x2 d0 = E0 * k0s + one;                                     \
                f32x2 d1 = E1 * k1s + one;                                     \
                f32x2 d2 = E2 * k2s + one;                                     \
                f32x2 d3 = E3 * k3s + one;                                     \
                f32x2 P01 = d0 * d1, P23 = d2 * d3;                            \
                f32x2 N01 = w0s * d1 + w1s * d0;                               \
                f32x2 N23 = w2s * d3 + w3s * d2;                               \
                f32x2 num = N01 * P23 + N23 * P01;                             \
                f32x2 P = P01 * P23;                                           \
                f32x2 rp;                                                      \
                rp.x = __builtin_amdgcn_rcpf(P.x);                             \
                rp.y = __builtin_amdgcn_rcpf(P.y);                             \
                S += num * rp;                                                 \
            }
            RBPK(eA0, eA1, eA2, eA3, accA[t])
            RBPK(eB0, eB1, eB2, eB3, accB[t])
            #undef RBPK
        }
    }

    // gather rows (static indices)
    float sc[4][4];
    #pragma unroll
    for (int t = 0; t < 4; ++t) {
        sc[t][0] = accA[t].x; sc[t][1] = accA[t].y;
        sc[t][2] = accB[t].x; sc[t][3] = accB[t].y;
    }

    // ---- softmax per row (lane holds k = 64t+lane); attn overlays strip ----
    #pragma unroll
    for (int r = 0; r < 4; ++r) {
        float x0 = -C2 * sc[0][r], x1 = -C2 * sc[1][r];
        float x2 = -C2 * sc[2][r], x3 = -C2 * sc[3][r];
        float m = fmaxf(fmaxf(x0, x1), fmaxf(x2, x3));
        #pragma unroll
        for (int off = 32; off; off >>= 1) m = fmaxf(m, __shfl_xor(m, off));
        float e0 = __builtin_amdgcn_exp2f(x0 - m);
        float e1 = __builtin_amdgcn_exp2f(x1 - m);
        float e2 = __builtin_amdgcn_exp2f(x2 - m);
        float e3 = __builtin_amdgcn_exp2f(x3 - m);
        float sum = (e0 + e1) + (e2 + e3);
        #pragma unroll
        for (int off = 32; off; off >>= 1) sum += __shfl_xor(sum, off);
        float inv = __builtin_amdgcn_rcpf(sum);
        strip[(r << 8) + lane]       = e0 * inv;   // own-wave ds ordering
        strip[(r << 8) + 64 + lane]  = e1 * inv;
        strip[(r << 8) + 128 + lane] = e2 * inv;
        strip[(r << 8) + 192 + lane] = e3 * inv;
    }

    // ---- PV: lane = h-pair (h = 2*lane, 2*lane+1); V f32 global (L1/L2-hot) ----
    float2 o0, o1, o2, o3;
    o0.x = o0.y = o1.x = o1.y = 0.f;
    o2.x = o2.y = o3.x = o3.y = 0.f;
    const float2* vp = (const float2*)(v_g + (size_t)b * 32768) + lane;
    #pragma unroll 4
    for (int j4 = 0; j4 < 64; ++j4) {
        float4 a0 = *(const float4*)(strip + (j4 << 2));          // row bcasts
        float4 a1 = *(const float4*)(strip + 256 + (j4 << 2));
        float4 a2 = *(const float4*)(strip + 512 + (j4 << 2));
        float4 a3 = *(const float4*)(strip + 768 + (j4 << 2));
        #pragma unroll
        for (int i = 0; i < 4; ++i) {
            float2 v2 = vp[((j4 << 2) + i) << 6];                 // 512B coalesced
            float c0 = (&a0.x)[i], c1 = (&a1.x)[i], c2 = (&a2.x)[i], c3 = (&a3.x)[i];
            o0.x = fmaf(c0, v2.x, o0.x); o0.y = fmaf(c0, v2.y, o0.y);
            o1.x = fmaf(c1, v2.x, o1.x); o1.y = fmaf(c1, v2.y, o1.y);
            o2.x = fmaf(c2, v2.x, o2.x); o2.y = fmaf(c2, v2.y, o2.y);
            o3.x = fmaf(c3, v2.x, o3.x); o3.y = fmaf(c3, v2.y, o3.y);
        }
    }

    float* ob = out + (size_t)(b * 256 + qr0) * 128 + (lane << 1);
    *(float2*)(ob)       = o0;
    *(float2*)(ob + 128) = o1;
    *(float2*)(ob + 256) = o2;
    *(float2*)(ob + 384) = o3;
}

extern "C" void kernel_launch(void* const* d_in, const int* in_sizes, int n_in,
                              void* d_out, int out_size, void* d_ws, size_t ws_size,
                              hipStream_t stream) {
    const float* q = (const float*)d_in[0];
    const float* k = (const float*)d_in[1];
    const float* v = (const float*)d_in[2];
    const float* w = (const float*)d_in[3];
    float* out = (float*)d_out;
    addattn_kernel<<<256, 512, 0, stream>>>(q, k, v, w, out);
}